// Round 1
// baseline (229.503 us; speedup 1.0000x reference)
//
#include <hip/hip_runtime.h>

#define IMG_H 512
#define IMG_W 512
#define NPLANES 48          // 16 batch * 3 channels
#define TX 64
#define TY 16
#define PW (TX + 10)        // 74
#define PH (TY + 10)        // 26
#define SSIM_C1 0.0001f     // 0.01^2
#define SSIM_C2 0.0009f     // 0.03^2

// Kernel A: per-tile separable 11x11 Gaussian convs (5 channels fused) + SSIM
// map + per-block partial sum into d_ws (one float per block, no atomics).
__global__ __launch_bounds__(256) void ssim_tile_kernel(
    const float* __restrict__ pred, const float* __restrict__ target,
    const float* __restrict__ window, float* __restrict__ partial)
{
    __shared__ float gS[16];
    __shared__ float predS[PH][PW];
    __shared__ float targS[PH][PW];
    __shared__ float4 H4[PH][TX];   // horizontal conv of (p, t, p*p, t*t)
    __shared__ float H12[PH][TX];   // horizontal conv of p*t
    __shared__ float wsum[4];

    const int tid = threadIdx.y * 64 + threadIdx.x;   // block = (64,4)

    // 1D gaussian = row sums of the 2D window (g normalized => row sum = g[i])
    if (tid < 11) {
        float s = 0.f;
        #pragma unroll
        for (int j = 0; j < 11; ++j) s += window[tid * 11 + j];
        gS[tid] = s;
    }

    const int plane = blockIdx.z;
    const int ty0 = blockIdx.y * TY;
    const int tx0 = blockIdx.x * TX;
    const float* pp = pred   + (size_t)plane * (IMG_H * IMG_W);
    const float* tp = target + (size_t)plane * (IMG_H * IMG_W);

    // Stage padded patch (zero-padded at image borders)
    for (int idx = tid; idx < PH * PW; idx += 256) {
        int r = idx / PW, c = idx - r * PW;
        int gy = ty0 + r - 5, gx = tx0 + c - 5;
        float pv = 0.f, tv = 0.f;
        if (gy >= 0 && gy < IMG_H && gx >= 0 && gx < IMG_W) {
            pv = pp[gy * IMG_W + gx];
            tv = tp[gy * IMG_W + gx];
        }
        predS[r][c] = pv;
        targS[r][c] = tv;
    }
    __syncthreads();

    float g[11];
    #pragma unroll
    for (int i = 0; i < 11; ++i) g[i] = gS[i];

    // Horizontal pass: PH x TX entries, 5 fused channels
    for (int idx = tid; idx < PH * TX; idx += 256) {
        int r = idx >> 6, c = idx & 63;   // TX == 64
        float m1 = 0.f, m2 = 0.f, s11 = 0.f, s22 = 0.f, s12 = 0.f;
        #pragma unroll
        for (int k = 0; k < 11; ++k) {
            float w = g[k];
            float p = predS[r][c + k];
            float t = targS[r][c + k];
            m1  = fmaf(w, p, m1);
            m2  = fmaf(w, t, m2);
            s11 = fmaf(w * p, p, s11);
            s22 = fmaf(w * t, t, s22);
            s12 = fmaf(w * p, t, s12);
        }
        H4[r][c]  = make_float4(m1, m2, s11, s22);
        H12[r][c] = s12;
    }
    __syncthreads();

    // Vertical pass: each thread owns 4 consecutive rows in one column
    // (sliding window over 14 H-rows amortizes LDS reads across the 4 outputs)
    const int cc = threadIdx.x;
    const int y0 = threadIdx.y * 4;
    float am1[4] = {0,0,0,0}, am2[4] = {0,0,0,0};
    float a11[4] = {0,0,0,0}, a22[4] = {0,0,0,0}, a12[4] = {0,0,0,0};
    #pragma unroll
    for (int r = 0; r < 14; ++r) {
        float4 h  = H4[y0 + r][cc];
        float h12 = H12[y0 + r][cc];
        #pragma unroll
        for (int j = 0; j < 4; ++j) {
            const int k = r - j;          // compile-time after full unroll
            if (k >= 0 && k < 11) {
                float w = g[k];
                am1[j] = fmaf(w, h.x,  am1[j]);
                am2[j] = fmaf(w, h.y,  am2[j]);
                a11[j] = fmaf(w, h.z,  a11[j]);
                a22[j] = fmaf(w, h.w,  a22[j]);
                a12[j] = fmaf(w, h12,  a12[j]);
            }
        }
    }

    // SSIM map + thread-local accumulation
    float acc = 0.f;
    #pragma unroll
    for (int j = 0; j < 4; ++j) {
        float mu1 = am1[j], mu2 = am2[j];
        float mu1_sq = mu1 * mu1, mu2_sq = mu2 * mu2, mu1_mu2 = mu1 * mu2;
        float sig1  = a11[j] - mu1_sq;
        float sig2  = a22[j] - mu2_sq;
        float sig12 = a12[j] - mu1_mu2;
        float num = (2.f * mu1_mu2 + SSIM_C1) * (2.f * sig12 + SSIM_C2);
        float den = (mu1_sq + mu2_sq + SSIM_C1) * (sig1 + sig2 + SSIM_C2);
        acc += num / den;
    }

    // Block reduction: wave64 shuffle + cross-wave via LDS
    #pragma unroll
    for (int off = 32; off > 0; off >>= 1)
        acc += __shfl_down(acc, off, 64);
    if ((tid & 63) == 0) wsum[tid >> 6] = acc;
    __syncthreads();
    if (tid == 0) {
        int bid = blockIdx.x + gridDim.x * (blockIdx.y + gridDim.y * blockIdx.z);
        partial[bid] = wsum[0] + wsum[1] + wsum[2] + wsum[3];
    }
}

// Kernel B: reduce the 12288 per-block partials (double accumulate) -> scalar
__global__ __launch_bounds__(256) void ssim_reduce_kernel(
    const float* __restrict__ partial, int n, float* __restrict__ out)
{
    double acc = 0.0;
    for (int i = threadIdx.x; i < n; i += 256) acc += (double)partial[i];
    #pragma unroll
    for (int off = 32; off > 0; off >>= 1)
        acc += __shfl_down(acc, off, 64);
    __shared__ double wsum[4];
    const int lane = threadIdx.x & 63, wid = threadIdx.x >> 6;
    if (lane == 0) wsum[wid] = acc;
    __syncthreads();
    if (threadIdx.x == 0) {
        double total = wsum[0] + wsum[1] + wsum[2] + wsum[3];
        const double N = (double)NPLANES * IMG_H * IMG_W;
        out[0] = (float)(1.0 - total / N);
    }
}

extern "C" void kernel_launch(void* const* d_in, const int* in_sizes, int n_in,
                              void* d_out, int out_size, void* d_ws, size_t ws_size,
                              hipStream_t stream)
{
    const float* pred   = (const float*)d_in[0];
    const float* target = (const float*)d_in[1];
    const float* window = (const float*)d_in[2];
    float* out = (float*)d_out;
    float* partial = (float*)d_ws;   // 12288 floats = 48 KiB

    dim3 grid(IMG_W / TX, IMG_H / TY, NPLANES);   // (8, 32, 48) = 12288 blocks
    dim3 block(64, 4);
    ssim_tile_kernel<<<grid, block, 0, stream>>>(pred, target, window, partial);

    const int nblocks = (IMG_W / TX) * (IMG_H / TY) * NPLANES;
    ssim_reduce_kernel<<<1, 256, 0, stream>>>(partial, nblocks, out);
}